// Round 6
// baseline (628.890 us; speedup 1.0000x reference)
//
#include <hip/hip_runtime.h>

// DualSPRTLinear: out = x @ W^T, W = dequant(ternary, group scales).
// bf16 MFMA GEMM M=8192, N=4096, K=4096, B stored [N][K] (B^T form).
// Round 5 (resubmit; R5 never ran — GPU acquisition timeout):
// R4's pipelined 8-phase schedule + FIX for the tail race: the final
// iteration froze the vmem queue so VMC(4) was a no-op and the last K-tile's
// ds_reads raced its global_load_lds writes. Now: main loop runs NITER-1
// iterations (stages unconditional), then a peeled tail that stages B(63)q23,
// drains vmcnt(0) once, and runs the 8 phases with reads only (no barriers
// needed: no LDS writes after the drain).

typedef __attribute__((ext_vector_type(8))) short      bf16x8;
typedef __attribute__((ext_vector_type(4))) float      f32x4;
typedef __attribute__((ext_vector_type(8))) float      f32x8;
typedef __attribute__((ext_vector_type(8))) unsigned short u16x8;
typedef __attribute__((ext_vector_type(4))) int        i32x4;

#define M_DIM 8192
#define N_DIM 4096
#define K_DIM 4096
#define BM 256
#define BN 256
#define BK 64
#define NT (K_DIM / BK)     // 64 K-tiles
#define NITER (NT / 2)      // 32: 2 tiles/iter (even->buf0, odd->buf1)
#define THREADS 512

#define LGKM(n) asm volatile("s_waitcnt lgkmcnt(" #n ")" ::: "memory")
#define VMC(n)  asm volatile("s_waitcnt vmcnt(" #n ")" ::: "memory")
#define SBAR    __builtin_amdgcn_s_barrier()
#define SCHB    __builtin_amdgcn_sched_barrier(0)
#define PRIO1   __builtin_amdgcn_s_setprio(1)
#define PRIO0   __builtin_amdgcn_s_setprio(0)

__device__ __forceinline__ unsigned short f2bf(float f) {
  union { float f; unsigned u; } v; v.f = f;
  unsigned u = v.u;
  u += 0x7FFFu + ((u >> 16) & 1u);
  return (unsigned short)(u >> 16);
}

__global__ void cvt_x_kernel(const float* __restrict__ x,
                             unsigned short* __restrict__ y, int n8) {
  int stride = gridDim.x * blockDim.x;
  for (int i = blockIdx.x * blockDim.x + threadIdx.x; i < n8; i += stride) {
    f32x8 f = ((const f32x8*)x)[i];
    u16x8 o;
#pragma unroll
    for (int j = 0; j < 8; ++j) o[j] = f2bf(f[j]);
    ((u16x8*)y)[i] = o;
  }
}

__global__ void cvt_w_kernel(const int* __restrict__ t, const float* __restrict__ s,
                             unsigned short* __restrict__ w, int n8) {
  int stride = gridDim.x * blockDim.x;
  for (int i = blockIdx.x * blockDim.x + threadIdx.x; i < n8; i += stride) {
    i32x4 a = ((const i32x4*)t)[2 * i + 0];
    i32x4 b = ((const i32x4*)t)[2 * i + 1];
    float sc = s[i >> 4];
    u16x8 o;
    o[0] = f2bf((float)a[0] * sc); o[1] = f2bf((float)a[1] * sc);
    o[2] = f2bf((float)a[2] * sc); o[3] = f2bf((float)a[3] * sc);
    o[4] = f2bf((float)b[0] * sc); o[5] = f2bf((float)b[1] * sc);
    o[6] = f2bf((float)b[2] * sc); o[7] = f2bf((float)b[3] * sc);
    ((u16x8*)w)[i] = o;
  }
}

// ---------------------------------------------------------------------------
// 256x256x64, 8 waves (2M x 4N), mfma_f32_16x16x32_bf16, wave tile 128x64.
// LDS 128 KiB: buf c at c*65536: A [256][64] (32KB) then B [256][64] (32KB);
// quarter q = 64 rows = 8KB = one STAGE (8 waves x global_load_lds x 16B).
// T2 swizzle: elem (row,col) at byte row*128 + 2*(col ^ (8*(row&7))); staged
// via linear global_load_lds dest + inverse-swizzled global source.
// Reads for phase p issued in phase p-1; counted LGKM leaves them in flight
// through the MFMA window. Counted VMC (never 0 mid-loop) retires stages
// exactly one phase before their readers (full queue audit in R4/R5 notes).
// ---------------------------------------------------------------------------
__global__ __launch_bounds__(THREADS, 2)
void gemm256_kernel(const unsigned short* __restrict__ A,
                    const unsigned short* __restrict__ B,
                    float* __restrict__ C) {
  extern __shared__ char smem[];

  const int tid  = threadIdx.x;
  const int lane = tid & 63;
  const int wave = tid >> 6;
  const int wm   = wave >> 2;
  const int wn   = wave & 3;

  // T1: XCD-bijective swizzle; grid = 512 (512 % 8 == 0).
  const int blk = blockIdx.x;
  const int wg  = (blk & 7) * 64 + (blk >> 3);
  const int bm  = wg >> 4;
  const int bn  = wg & 15;

  const int srow = tid >> 3;
  const int scol = 8 * ((tid & 7) ^ (srow & 7));
  const unsigned short* Ap = A + (size_t)(bm * BM + srow) * K_DIM + scol;
  const unsigned short* Bp = B + (size_t)(bn * BN + srow) * K_DIM + scol;
  const int ldsWave = wave * 1024;

  auto STAGE = [&](int buf, int ab, int t, int q) {
    const unsigned short* src =
        (ab == 0 ? Ap : Bp) + (size_t)q * 64 * K_DIM + (size_t)t * BK;
    char* dst = smem + buf * 65536 + ab * 32768 + q * 8192 + ldsWave;
    __builtin_amdgcn_global_load_lds(
        (const __attribute__((address_space(1))) void*)src,
        (__attribute__((address_space(3))) void*)dst, 16, 0, 0);
  };

  const int r   = lane & 15;
  const int kq  = lane >> 4;
  const int swz = (lane & 7) << 3;
  auto RD_A = [&](int buf, int mf, int ks) -> bf16x8 {
    const int row = wm * 128 + mf * 16 + r;
    const int col = (ks * 32 + kq * 8) ^ swz;
    return *(const bf16x8*)(smem + buf * 65536 + (row * 64 + col) * 2);
  };
  auto RD_B = [&](int buf, int nf, int ks) -> bf16x8 {
    const int row = wn * 64 + nf * 16 + r;
    const int col = (ks * 32 + kq * 8) ^ swz;
    return *(const bf16x8*)(smem + buf * 65536 + 32768 + (row * 64 + col) * 2);
  };

  f32x4 acc[8][4];
  const f32x4 fzero = {0.f, 0.f, 0.f, 0.f};
#pragma unroll
  for (int mf = 0; mf < 8; ++mf)
#pragma unroll
    for (int nf = 0; nf < 4; ++nf) acc[mf][nf] = fzero;

  auto MFMA_Q = [&](bf16x8 (&af)[4][2], bf16x8 (&bf)[2][2], int mo, int no) {
#pragma unroll
    for (int mf = 0; mf < 4; ++mf)
#pragma unroll
      for (int nf = 0; nf < 2; ++nf)
#pragma unroll
        for (int ks = 0; ks < 2; ++ks)
          acc[mo + mf][no + nf] = __builtin_amdgcn_mfma_f32_16x16x32_bf16(
              af[mf][ks], bf[nf][ks], acc[mo + mf][no + nf], 0, 0, 0);
  };

  bf16x8 aA[4][2], aB[4][2], bA0[2][2], bA1[2][2], bB[2][2];

  // ---- prologue: A(0),B(0),A(1) full; B(1) q0,q1.  (B(1)q23 in Ph1.) ----
#pragma unroll
  for (int q = 0; q < 4; ++q) STAGE(0, 0, 0, q);
#pragma unroll
  for (int q = 0; q < 4; ++q) STAGE(0, 1, 0, q);
#pragma unroll
  for (int q = 0; q < 4; ++q) STAGE(1, 0, 1, q);
  STAGE(1, 1, 1, 0); STAGE(1, 1, 1, 1);
  VMC(6);                      // retire A(0),B(0); keep A(1),B(1)q01 in flight
  SBAR;
  // prologue reads for Ph1: aLo(0), b01(0)
#pragma unroll
  for (int mf = 0; mf < 4; ++mf)
#pragma unroll
    for (int ks = 0; ks < 2; ++ks) aA[mf][ks] = RD_A(0, mf, ks);
#pragma unroll
  for (int nf = 0; nf < 2; ++nf)
#pragma unroll
    for (int ks = 0; ks < 2; ++ks) bA0[nf][ks] = RD_B(0, nf, ks);

  // ======================= main loop: iterations 0..NITER-2 =================
  for (int i = 0; i + 1 < NITER; ++i) {
    const int e = 2 * i, o = e + 1;

    // Ph1: MFMA(m0-3,n0-1)e [aA,bA0] | read bHi(e)->bB | stage B(o)q23
#pragma unroll
    for (int nf = 0; nf < 2; ++nf)
#pragma unroll
      for (int ks = 0; ks < 2; ++ks) bB[nf][ks] = RD_B(0, nf + 2, ks);
    STAGE(1, 1, o, 2); STAGE(1, 1, o, 3);
    SBAR; LGKM(4); SCHB; PRIO1;
    MFMA_Q(aA, bA0, 0, 0);
    PRIO0; SBAR;

    // Ph2: MFMA(m0-3,n2-3)e [aA,bB] | read aHi(e)->aB | stage A(e+2)q02
#pragma unroll
    for (int mf = 0; mf < 4; ++mf)
#pragma unroll
      for (int ks = 0; ks < 2; ++ks) aB[mf][ks] = RD_A(0, mf + 4, ks);
    STAGE(0, 0, e + 2, 0); STAGE(0, 0, e + 2, 2);
    SBAR; LGKM(8); SCHB; PRIO1;
    MFMA_Q(aA, bB, 0, 2);
    PRIO0; VMC(4); SBAR;

    // Ph3: MFMA(m4-7,n2-3)e [aB,bB] | read aLo(o)->aA | stage B(e+2)q01
#pragma unroll
    for (int mf = 0; mf < 4; ++mf)
#pragma unroll
      for (int ks = 0; ks < 2; ++ks) aA[mf][ks] = RD_A(1, mf, ks);
    STAGE(0, 1, e + 2, 0); STAGE(0, 1, e + 2, 1);
    SBAR; LGKM(8); SCHB; PRIO1;
    MFMA_Q(aB, bB, 4, 2);
    PRIO0; VMC(4); SBAR;

    // Ph4: MFMA(m4-7,n0-1)e [aB,bA0] | read b01(o)->bA1 | stage A(e+2)q13
#pragma unroll
    for (int nf = 0; nf < 2; ++nf)
#pragma unroll
      for (int ks = 0; ks < 2; ++ks) bA1[nf][ks] = RD_B(1, nf, ks);
    STAGE(0, 0, e + 2, 1); STAGE(0, 0, e + 2, 3);
    SBAR; LGKM(12); SCHB; PRIO1;
    MFMA_Q(aB, bA0, 4, 0);
    PRIO0; SBAR;

    // Ph5: MFMA(m0-3,n0-1)o [aA,bA1] | read bHi(o)->bB | stage B(e+2)q23
#pragma unroll
    for (int nf = 0; nf < 2; ++nf)
#pragma unroll
      for (int ks = 0; ks < 2; ++ks) bB[nf][ks] = RD_B(1, nf + 2, ks);
    STAGE(0, 1, e + 2, 2); STAGE(0, 1, e + 2, 3);
    SBAR; LGKM(4); SCHB; PRIO1;
    MFMA_Q(aA, bA1, 0, 0);
    PRIO0; SBAR;

    // Ph6: MFMA(m0-3,n2-3)o [aA,bB] | read aHi(o)->aB | stage A(o+2)q02
#pragma unroll
    for (int mf = 0; mf < 4; ++mf)
#pragma unroll
      for (int ks = 0; ks < 2; ++ks) aB[mf][ks] = RD_A(1, mf + 4, ks);
    STAGE(1, 0, o + 2, 0); STAGE(1, 0, o + 2, 2);
    SBAR; LGKM(8); SCHB; PRIO1;
    MFMA_Q(aA, bB, 0, 2);
    PRIO0; VMC(4); SBAR;

    // Ph7: MFMA(m4-7,n2-3)o [aB,bB] | read aLo(e+2)->aA | stage B(o+2)q01
#pragma unroll
    for (int mf = 0; mf < 4; ++mf)
#pragma unroll
      for (int ks = 0; ks < 2; ++ks) aA[mf][ks] = RD_A(0, mf, ks);
    STAGE(1, 1, o + 2, 0); STAGE(1, 1, o + 2, 1);
    SBAR; LGKM(8); SCHB; PRIO1;
    MFMA_Q(aB, bB, 4, 2);
    PRIO0; VMC(4); SBAR;

    // Ph8: MFMA(m4-7,n0-1)o [aB,bA1] | read b01(e+2)->bA0 | stage A(o+2)q13
#pragma unroll
    for (int nf = 0; nf < 2; ++nf)
#pragma unroll
      for (int ks = 0; ks < 2; ++ks) bA0[nf][ks] = RD_B(0, nf, ks);
    STAGE(1, 0, o + 2, 1); STAGE(1, 0, o + 2, 3);
    SBAR; LGKM(12); SCHB; PRIO1;
    MFMA_Q(aB, bA1, 4, 0);
    PRIO0; SBAR;
  }

  // ======================= peeled tail: tiles NT-2 (buf0), NT-1 (buf1) ======
  // Stage the one missing piece, then drain EVERYTHING once. After this
  // point there are no LDS writes, so no barriers are needed.
  STAGE(1, 1, NT - 1, 2); STAGE(1, 1, NT - 1, 3);
  VMC(0); SBAR;

  // tPh1
#pragma unroll
  for (int nf = 0; nf < 2; ++nf)
#pragma unroll
    for (int ks = 0; ks < 2; ++ks) bB[nf][ks] = RD_B(0, nf + 2, ks);
  LGKM(4); SCHB; PRIO1; MFMA_Q(aA, bA0, 0, 0); PRIO0;
  // tPh2
#pragma unroll
  for (int mf = 0; mf < 4; ++mf)
#pragma unroll
    for (int ks = 0; ks < 2; ++ks) aB[mf][ks] = RD_A(0, mf + 4, ks);
  LGKM(8); SCHB; PRIO1; MFMA_Q(aA, bB, 0, 2); PRIO0;
  // tPh3
#pragma unroll
  for (int mf = 0; mf < 4; ++mf)
#pragma unroll
    for (int ks = 0; ks < 2; ++ks) aA[mf][ks] = RD_A(1, mf, ks);
  LGKM(8); SCHB; PRIO1; MFMA_Q(aB, bB, 4, 2); PRIO0;
  // tPh4
#pragma unroll
  for (int nf = 0; nf < 2; ++nf)
#pragma unroll
    for (int ks = 0; ks < 2; ++ks) bA1[nf][ks] = RD_B(1, nf, ks);
  LGKM(12); SCHB; PRIO1; MFMA_Q(aB, bA0, 4, 0); PRIO0;
  // tPh5
#pragma unroll
  for (int nf = 0; nf < 2; ++nf)
#pragma unroll
    for (int ks = 0; ks < 2; ++ks) bB[nf][ks] = RD_B(1, nf + 2, ks);
  LGKM(4); SCHB; PRIO1; MFMA_Q(aA, bA1, 0, 0); PRIO0;
  // tPh6
#pragma unroll
  for (int mf = 0; mf < 4; ++mf)
#pragma unroll
    for (int ks = 0; ks < 2; ++ks) aB[mf][ks] = RD_A(1, mf + 4, ks);
  LGKM(8); SCHB; PRIO1; MFMA_Q(aA, bB, 0, 2); PRIO0;
  // tPh7
  LGKM(0); SCHB; PRIO1; MFMA_Q(aB, bB, 4, 2); PRIO0;
  // tPh8
  PRIO1; MFMA_Q(aB, bA1, 4, 0); PRIO0;

  // ---- epilogue: C/D map col = lane&15, row = (lane>>4)*4 + j ----
  const int r4 = (lane >> 4) * 4;
  const int cc = lane & 15;
  const size_t row0 = (size_t)bm * BM + wm * 128;
  const size_t col0 = (size_t)bn * BN + wn * 64;
#pragma unroll
  for (int mf = 0; mf < 8; ++mf)
#pragma unroll
    for (int nf = 0; nf < 4; ++nf)
#pragma unroll
      for (int j = 0; j < 4; ++j)
        C[(row0 + mf * 16 + r4 + j) * N_DIM + col0 + nf * 16 + cc] =
            acc[mf][nf][j];
}

extern "C" void kernel_launch(void* const* d_in, const int* in_sizes, int n_in,
                              void* d_out, int out_size, void* d_ws, size_t ws_size,
                              hipStream_t stream) {
  const float* x      = (const float*)d_in[0];
  const int*   tern   = (const int*)d_in[1];
  const float* scales = (const float*)d_in[2];
  float* out = (float*)d_out;

  unsigned short* xb = (unsigned short*)d_ws;
  unsigned short* wb = (unsigned short*)d_ws + (size_t)M_DIM * K_DIM;

  cvt_x_kernel<<<2048, 256, 0, stream>>>(x, xb, M_DIM * K_DIM / 8);
  cvt_w_kernel<<<2048, 256, 0, stream>>>(tern, scales, wb, N_DIM * K_DIM / 8);

  hipFuncSetAttribute((const void*)gemm256_kernel,
                      hipFuncAttributeMaxDynamicSharedMemorySize, 131072);
  const int grid = (M_DIM / BM) * (N_DIM / BN);  // 32 * 16 = 512
  gemm256_kernel<<<grid, THREADS, 131072, stream>>>(xb, wb, out);
}